// Round 1
// baseline (242.184 us; speedup 1.0000x reference)
//
#include <hip/hip_runtime.h>
#include <math.h>

#define H_ 56
#define W_ 56
#define CIN 256
#define COUT 256
#define NB 8
#define SPIX 3136
#define KG 2304
#define MTOT 25088

typedef __bf16 v8bf __attribute__((ext_vector_type(8)));
typedef float  v4f  __attribute__((ext_vector_type(4)));

// ---------- pre-kernel 1: NCHW fp32 -> NHWC bf16
__global__ __launch_bounds__(256) void prep_x(const float* __restrict__ x,
                                              __bf16* __restrict__ xb) {
    __shared__ float tile[64][65];
    const int n = blockIdx.z, c0 = blockIdx.y * 64, s0 = blockIdx.x * 64;
    const int tid = threadIdx.x;
    const float* xp = x + (size_t)n * CIN * SPIX;
    __bf16* xo = xb + (size_t)n * SPIX * CIN;
#pragma unroll
    for (int i = 0; i < 16; ++i) {
        int idx = tid + i * 256;
        int cr = idx >> 6, sc = idx & 63;
        tile[cr][sc] = xp[(c0 + cr) * SPIX + s0 + sc];
    }
    __syncthreads();
#pragma unroll
    for (int i = 0; i < 16; ++i) {
        int idx = tid + i * 256;
        int sr = idx >> 6, cc = idx & 63;
        xo[(s0 + sr) * CIN + c0 + cc] = (__bf16)tile[cc][sr];
    }
}

// ---------- pre-kernel 2: weight (Cout,Cin,3,3) fp32 -> Bp[o][tap*256+c] bf16
__global__ __launch_bounds__(256) void prep_w(const float* __restrict__ w,
                                              __bf16* __restrict__ bp) {
    const int i = blockIdx.x * 256 + threadIdx.x;
    if (i < COUT * KG) {
        const int o = i / KG;
        const int rem = i - o * KG;
        const int c = rem / 9;
        const int tap = rem - c * 9;
        bp[(size_t)o * KG + tap * 256 + c] = (__bf16)w[i];
    }
}

// ---------- fused deformable-gather + bf16 MFMA GEMM
// Block = 64 pixels x 256 outputs, K=2304 full (no atomics, no V buffer).
// XCD swizzle maps 49 consecutive blocks (= exactly one image, 1.6 MB of xb)
// onto one XCD's L2, so the 462 MB of logical gather reads stay L2-resident.
// A-subtile (64x64 per K-step) is constructed in-register from 4 bilinear
// gathers and written to LDS with the same XOR-chunk swizzle gemm_v used.
// B fragments are read straight from L2-resident bp (no B staging).
// T14 split: gathers for step ks+1 issue before the MFMA barrier of step ks.
__global__ __launch_bounds__(512, 4) void mdcn_fused2(
    const __bf16* __restrict__ xb,     // NHWC bf16
    const float*  __restrict__ offs,   // (N,18,56,56)
    const float*  __restrict__ msk,    // (N,9,56,56)
    const __bf16* __restrict__ bp,     // [COUT][KG]  (tap-major K)
    const float*  __restrict__ bias,
    float*        __restrict__ out)    // (N,256,56,56)
{
    __shared__ __align__(16) char smem[26624];     // As 8K | sB 9K | sW 9K
    __bf16* As = (__bf16*)smem;                    // [64 pix][64 k], chunk-swizzled
    int*    sB = (int*)(smem + 8192);              // [9][64][4] gather bases
    float*  sW = (float*)(smem + 17408);           // [9][64][4] bilinear weights

    const int tid  = threadIdx.x;
    const int lane = tid & 63, wv = tid >> 6;      // 8 waves
    const int wm = wv & 1, wn = wv >> 1;           // m-half 32, n-quarter 64
    const int orig = blockIdx.x;
    // bijective XCD swizzle: 392 = 8 * 49; image n == (orig & 7)
    const int n_img = orig & 7;
    const int sblk  = (orig >> 3) << 6;            // pixel offset within image
    const int m0    = n_img * SPIX + sblk;
    const int l15 = lane & 15, q = lane >> 4;

    // ---- phase 0: bilinear params for 64 pixels x 9 taps
    for (int idx = tid; idx < 576; idx += 512) {
        const int tap = idx >> 6, pl = idx & 63;
        const int s   = sblk + pl;
        const int h   = s / W_;
        const int w   = s - h * W_;
        const int kY = tap / 3, kX = tap - kY * 3;
        const float dy = offs[n_img * (18 * SPIX) + (2 * tap) * SPIX + s];
        const float dx = offs[n_img * (18 * SPIX) + (2 * tap + 1) * SPIX + s];
        const float mk = msk[n_img * (9 * SPIX) + tap * SPIX + s];
        const float py = dy + (float)(kY + h - 1);  // PAD=1,STRIDE=1,DIL=1
        const float px = dx + (float)(kX + w - 1);
        const float fy0 = floorf(py), fx0 = floorf(px);
        const int y0 = (int)fy0, x0 = (int)fx0;
        const float wy1 = py - fy0, wx1 = px - fx0;
        const float wy0 = 1.0f - wy1, wx0 = 1.0f - wx1;
#pragma unroll
        for (int t = 0; t < 4; ++t) {
            const int yi = y0 + (t >> 1), xi = x0 + (t & 1);
            const bool valid = (yi >= 0) & (yi < H_) & (xi >= 0) & (xi < W_);
            const int yc = min(max(yi, 0), H_ - 1);
            const int xc = min(max(xi, 0), W_ - 1);
            sB[idx * 4 + t] = (n_img * SPIX + yc * W_ + xc) * CIN;
            sW[idx * 4 + t] = valid
                ? (((t >> 1) ? wy1 : wy0) * ((t & 1) ? wx1 : wx0) * mk) : 0.0f;
        }
    }

    v4f acc[2][4];
#pragma unroll
    for (int i = 0; i < 2; ++i)
#pragma unroll
        for (int j = 0; j < 4; ++j) acc[i][j] = (v4f)0.f;

    __syncthreads();                               // params ready

    // gather thread mapping: pixel pl, channel-group cg (8 ch each)
    const int pl = tid >> 3, cg = tid & 7;
    __bf16* awr = As + pl * 64 + ((cg ^ (pl & 7)) << 3);   // swizzled A slot

    // prefetch gathers for step 0 (tap 0, channel quarter 0)
    v8bf g0, g1, g2, g3;
    float w0, w1, w2, w3;
    {
        const int pb = pl * 4;
        const int4   cb = *(const int4*)(sB + pb);
        const float4 cw = *(const float4*)(sW + pb);
        const int co = cg * 8;
        g0 = *(const v8bf*)(xb + cb.x + co);
        g1 = *(const v8bf*)(xb + cb.y + co);
        g2 = *(const v8bf*)(xb + cb.z + co);
        g3 = *(const v8bf*)(xb + cb.w + co);
        w0 = cw.x; w1 = cw.y; w2 = cw.z; w3 = cw.w;
    }

#pragma unroll 1
    for (int ks = 0; ks < 36; ++ks) {
        // combine the in-flight gathers (VALU; overlaps other waves' MFMA)
        v8bf r;
#pragma unroll
        for (int j = 0; j < 8; ++j)
            r[j] = (__bf16)(w0 * (float)g0[j] + w1 * (float)g1[j]
                          + w2 * (float)g2[j] + w3 * (float)g3[j]);

        __syncthreads();                           // all waves done reading As
        *(v8bf*)awr = r;

        if (ks < 35) {                             // issue gathers for next step
            const int ks1 = ks + 1;
            const int pb1 = ((ks1 >> 2) * 64 + pl) * 4;   // tap = ks1/4
            const int4   cb = *(const int4*)(sB + pb1);
            const float4 cw = *(const float4*)(sW + pb1);
            const int coff = ((ks1 & 3) << 6) + cg * 8;   // channel quarter
            g0 = *(const v8bf*)(xb + cb.x + coff);
            g1 = *(const v8bf*)(xb + cb.y + coff);
            g2 = *(const v8bf*)(xb + cb.z + coff);
            g3 = *(const v8bf*)(xb + cb.w + coff);
            w0 = cw.x; w1 = cw.y; w2 = cw.z; w3 = cw.w;
        }
        __syncthreads();                           // As ready

        const int k0 = ks << 6;
#pragma unroll
        for (int kf = 0; kf < 2; ++kf) {
            v8bf afr[2], bfr[4];
#pragma unroll
            for (int mt = 0; mt < 2; ++mt) {
                const int row = wm * 32 + mt * 16 + l15;
                const int pch = (kf * 4 + q) ^ (row & 7);
                afr[mt] = *(const v8bf*)(As + row * 64 + pch * 8);
            }
#pragma unroll
            for (int nt = 0; nt < 4; ++nt) {
                const int ro = wn * 64 + nt * 16 + l15;
                bfr[nt] = *(const v8bf*)(bp + (size_t)ro * KG + k0
                                          + (kf * 4 + q) * 8);
            }
#pragma unroll
            for (int mt = 0; mt < 2; ++mt)
#pragma unroll
                for (int nt = 0; nt < 4; ++nt)
                    acc[mt][nt] = __builtin_amdgcn_mfma_f32_16x16x32_bf16(
                        afr[mt], bfr[nt], acc[mt][nt], 0, 0, 0);
        }
    }

    // ---- epilogue (identical geometry to verified gemm_v)
    __syncthreads();
    float* epi = (float*)(smem + wv * 2176);
    const int s_base = sblk + wm * 32;
    float* outb = out + (size_t)n_img * COUT * SPIX + s_base;

#pragma unroll
    for (int nt = 0; nt < 4; ++nt) {
        const float bv = bias[wn * 64 + nt * 16 + l15];
#pragma unroll
        for (int mt = 0; mt < 2; ++mt)
#pragma unroll
            for (int r = 0; r < 4; ++r)
                epi[(mt * 16 + q * 4 + r) * 17 + l15] = acc[mt][nt][r] + bv;
        __syncthreads();
        const int m = lane & 31, oh = lane >> 5;
#pragma unroll
        for (int oc = 0; oc < 8; ++oc) {
            const float v = epi[m * 17 + oc * 2 + oh];
            const int o = wn * 64 + nt * 16 + oc * 2 + oh;
            outb[(size_t)o * SPIX + m] = v;
        }
        __syncthreads();
    }
}

// ---------- fp32 fallback (round-1 verified, no workspace)
#define BM 64
#define BN 64
#define BKF 32
#define AST 68
#define BST 68
#define CST 65
__global__ __launch_bounds__(256) void mdcn_fallback(
    const float* __restrict__ xs, const float* __restrict__ offs,
    const float* __restrict__ msk, const float* __restrict__ wraw,
    const float* __restrict__ bias, float* __restrict__ out)
{
    __shared__ float smem[BKF * AST + BKF * BST];
    __shared__ int   sBase[4][BM];
    __shared__ float sWgt[4][BM];
    float (*At)[AST] = (float (*)[AST])smem;
    float (*Bt)[BST] = (float (*)[BST])(smem + BKF * AST);
    float (*Cs)[CST] = (float (*)[CST])smem;
    const int tid = threadIdx.x;
    const int m0 = blockIdx.x * BM;
    const int o0 = blockIdx.y * BN;
    const int n  = m0 / SPIX;
    const int s0 = m0 - n * SPIX;
    const int tx = tid & 15, ty = tid >> 4;
    float acc[4][4] = {};
    for (int k = 0; k < 9; ++k) {
        if (tid < BM) {
            const int s = s0 + tid;
            const int h = s / W_;
            const int w = s - h * W_;
            const int kY = k / 3, kX = k - kY * 3;
            const float dy = offs[(size_t)n * (18 * SPIX) + (size_t)(2 * k) * SPIX + s];
            const float dx = offs[(size_t)n * (18 * SPIX) + (size_t)(2 * k + 1) * SPIX + s];
            const float mk = msk[(size_t)n * (9 * SPIX) + (size_t)k * SPIX + s];
            const float py = dy + (float)(kY + h - 1);
            const float px = dx + (float)(kX + w - 1);
            const float fy0 = floorf(py), fx0 = floorf(px);
            const int y0 = (int)fy0, x0 = (int)fx0;
            const float wy1 = py - fy0, wx1 = px - fx0;
            const float wy0 = 1.0f - wy1, wx0 = 1.0f - wx1;
#pragma unroll
            for (int t = 0; t < 4; ++t) {
                const int yi = y0 + (t >> 1), xi = x0 + (t & 1);
                const bool valid = (yi >= 0) & (yi < H_) & (xi >= 0) & (xi < W_);
                const int yc = min(max(yi, 0), H_ - 1);
                const int xc = min(max(xi, 0), W_ - 1);
                float wt = ((t >> 1) ? wy1 : wy0) * ((t & 1) ? wx1 : wx0) * mk;
                sBase[t][tid] = n * (CIN * SPIX) + yc * W_ + xc;
                sWgt[t][tid] = valid ? wt : 0.0f;
            }
        }
        __syncthreads();
        for (int c0 = 0; c0 < CIN; c0 += BKF) {
#pragma unroll
            for (int i = 0; i < 8; ++i) {
                int idx = tid + i * 256;
                int row = idx >> 5, cc = idx & 31;
                int ce = (c0 + cc) * SPIX;
                At[cc][row] = sWgt[0][row] * xs[sBase[0][row] + ce]
                            + sWgt[1][row] * xs[sBase[1][row] + ce]
                            + sWgt[2][row] * xs[sBase[2][row] + ce]
                            + sWgt[3][row] * xs[sBase[3][row] + ce];
            }
#pragma unroll
            for (int i = 0; i < 8; ++i) {
                int idx = tid + i * 256;
                int kf = idx >> 6, o = idx & 63;
                Bt[kf][o] = wraw[(size_t)(o0 + o) * KG + (c0 + kf) * 9 + k];
            }
            __syncthreads();
#pragma unroll
            for (int kf = 0; kf < BKF; ++kf) {
                const float4 a = *(const float4*)&At[kf][ty * 4];
                const float4 b = *(const float4*)&Bt[kf][tx * 4];
                acc[0][0] = fmaf(a.x, b.x, acc[0][0]); acc[0][1] = fmaf(a.x, b.y, acc[0][1]);
                acc[0][2] = fmaf(a.x, b.z, acc[0][2]); acc[0][3] = fmaf(a.x, b.w, acc[0][3]);
                acc[1][0] = fmaf(a.y, b.x, acc[1][0]); acc[1][1] = fmaf(a.y, b.y, acc[1][1]);
                acc[1][2] = fmaf(a.y, b.z, acc[1][2]); acc[1][3] = fmaf(a.y, b.w, acc[1][3]);
                acc[2][0] = fmaf(a.z, b.x, acc[2][0]); acc[2][1] = fmaf(a.z, b.y, acc[2][1]);
                acc[2][2] = fmaf(a.z, b.z, acc[2][2]); acc[2][3] = fmaf(a.z, b.w, acc[2][3]);
                acc[3][0] = fmaf(a.w, b.x, acc[3][0]); acc[3][1] = fmaf(a.w, b.y, acc[3][1]);
                acc[3][2] = fmaf(a.w, b.z, acc[3][2]); acc[3][3] = fmaf(a.w, b.w, acc[3][3]);
            }
            __syncthreads();
        }
    }
#pragma unroll
    for (int i = 0; i < 4; ++i)
#pragma unroll
        for (int j = 0; j < 4; ++j)
            Cs[ty * 4 + i][tx * 4 + j] = acc[i][j] + bias[o0 + tx * 4 + j];
    __syncthreads();
    const int pix = tid & 63, ob = tid >> 6;
    float* outp = out + (size_t)n * COUT * SPIX + s0 + pix;
#pragma unroll
    for (int r = 0; r < 16; ++r) {
        int o = r * 4 + ob;
        outp[(size_t)(o0 + o) * SPIX] = Cs[pix][o];
    }
}

extern "C" void kernel_launch(void* const* d_in, const int* in_sizes, int n_in,
                              void* d_out, int out_size, void* d_ws, size_t ws_size,
                              hipStream_t stream) {
    const float* x    = (const float*)d_in[0];
    const float* offs = (const float*)d_in[1];
    const float* msk  = (const float*)d_in[2];
    const float* w    = (const float*)d_in[3];
    const float* bias = (const float*)d_in[4];
    float* out = (float*)d_out;

    const size_t xb_bytes = (size_t)NB * SPIX * CIN * sizeof(__bf16);    // 12.85 MB
    const size_t bp_bytes = (size_t)KG * COUT * sizeof(__bf16);          // 1.18 MB

    if (ws_size >= xb_bytes + bp_bytes) {
        __bf16* xb = (__bf16*)d_ws;
        __bf16* bp = (__bf16*)((char*)d_ws + xb_bytes);
        prep_x<<<dim3(49, 4, 8), 256, 0, stream>>>(x, xb);
        prep_w<<<dim3((COUT * KG + 255) / 256), 256, 0, stream>>>(w, bp);
        mdcn_fused2<<<dim3(MTOT / 64), 512, 0, stream>>>(
            xb, offs, msk, bp, bias, out);
    } else {
        mdcn_fallback<<<dim3(MTOT / BM, COUT / BN), 256, 0, stream>>>(
            x, offs, msk, w, bias, out);
    }
}

// Round 2
// 162.818 us; speedup vs baseline: 1.4874x; 1.4874x over previous
//
#include <hip/hip_runtime.h>
#include <math.h>

#define H_ 56
#define W_ 56
#define CIN 256
#define COUT 256
#define NB 8
#define SPIX 3136
#define KG 2304
#define MTOT 25088
#define MT 128
#define NBLK 196   // MTOT / MT

typedef __bf16 v8bf __attribute__((ext_vector_type(8)));
typedef float  v4f  __attribute__((ext_vector_type(4)));

__device__ __forceinline__ void async_copy16(const void* g, void* l) {
    __builtin_amdgcn_global_load_lds(
        (const __attribute__((address_space(1))) void*)g,
        (__attribute__((address_space(3))) void*)l, 16, 0, 0);
}

// ---------- pre-kernel 1: NCHW fp32 -> NHWC bf16
__global__ __launch_bounds__(256) void prep_x(const float* __restrict__ x,
                                              __bf16* __restrict__ xb) {
    __shared__ float tile[64][65];
    const int n = blockIdx.z, c0 = blockIdx.y * 64, s0 = blockIdx.x * 64;
    const int tid = threadIdx.x;
    const float* xp = x + (size_t)n * CIN * SPIX;
    __bf16* xo = xb + (size_t)n * SPIX * CIN;
#pragma unroll
    for (int i = 0; i < 16; ++i) {
        int idx = tid + i * 256;
        int cr = idx >> 6, sc = idx & 63;
        tile[cr][sc] = xp[(c0 + cr) * SPIX + s0 + sc];
    }
    __syncthreads();
#pragma unroll
    for (int i = 0; i < 16; ++i) {
        int idx = tid + i * 256;
        int sr = idx >> 6, cc = idx & 63;
        xo[(s0 + sr) * CIN + c0 + cc] = (__bf16)tile[cc][sr];
    }
}

// ---------- pre-kernel 2: weight (Cout,Cin,3,3) fp32 -> Bp[o][tap*256+c] bf16
__global__ __launch_bounds__(256) void prep_w(const float* __restrict__ w,
                                              __bf16* __restrict__ bp) {
    const int i = blockIdx.x * 256 + threadIdx.x;
    if (i < COUT * KG) {
        const int o = i / KG;
        const int rem = i - o * KG;
        const int c = rem / 9;
        const int tap = rem - c * 9;
        bp[(size_t)o * KG + tap * 256 + c] = (__bf16)w[i];
    }
}

// ---------- bilinear params for taps [t0, t0+ntaps) of this block's 128 px.
// Stores UNCLAMPED spatial base (n*SPIX + y0*W + x0); invalid corners carry
// weight 0 and read into the guard bands around xb (values never used).
__device__ __forceinline__ void compute_params(
    const float* __restrict__ offs, const float* __restrict__ msk,
    int m0, int t0, int ntaps, int* sS, float4* sW, int tid)
{
    for (int idx = tid; idx < ntaps * MT; idx += 512) {
        const int tl = idx >> 7, pl = idx & 127;
        const int tap = t0 + tl;
        const int pg = m0 + pl;
        const int n  = pg / SPIX;
        const int s  = pg - n * SPIX;
        const int h  = s / W_, w = s - h * W_;
        const int kY = tap / 3, kX = tap - kY * 3;
        const float dy = offs[n * (18 * SPIX) + (2 * tap) * SPIX + s];
        const float dx = offs[n * (18 * SPIX) + (2 * tap + 1) * SPIX + s];
        const float mk = msk[n * (9 * SPIX) + tap * SPIX + s];
        const float py = dy + (float)(kY + h - 1);   // PAD=1,STRIDE=1,DIL=1
        const float px = dx + (float)(kX + w - 1);
        const float fy0 = floorf(py), fx0 = floorf(px);
        const int y0 = (int)fy0, x0 = (int)fx0;
        const float wy1 = py - fy0, wx1 = px - fx0;
        const float wy0 = 1.f - wy1, wx0 = 1.f - wx1;
        const bool yv0 = (y0 >= 0) & (y0 < H_);
        const bool yv1 = (y0 + 1 >= 0) & (y0 + 1 < H_);
        const bool xv0 = (x0 >= 0) & (x0 < W_);
        const bool xv1 = (x0 + 1 >= 0) & (x0 + 1 < W_);
        float4 wt;
        wt.x = (yv0 & xv0) ? wy0 * wx0 * mk : 0.f;
        wt.y = (yv0 & xv1) ? wy0 * wx1 * mk : 0.f;
        wt.z = (yv1 & xv0) ? wy1 * wx0 * mk : 0.f;
        wt.w = (yv1 & xv1) ? wy1 * wx1 * mk : 0.f;
        sS[idx] = (n * SPIX + y0 * W_ + x0) * CIN;
        sW[idx] = wt;
    }
}

// ---------- fused deformable-gather + bf16 MFMA GEMM, gemm_v skeleton.
// 128 px x 256 out per block, grid 196 (one round). B staged to LDS via
// global_load_lds (XOR-swizzled source, verified pattern); A built from 8
// register gathers (prefetched one k-step ahead) + combine + swizzled
// ds_write. 2 barriers / k-step, 32 MFMA per wave per k-step.
__global__ __launch_bounds__(512, 2) void mdcn_fused3(
    const __bf16* __restrict__ xb,     // NHWC bf16 (guarded +/- 4MB)
    const float*  __restrict__ offs,
    const float*  __restrict__ msk,
    const __bf16* __restrict__ bp,     // [COUT][KG] tap-major K
    const float*  __restrict__ bias,
    float*        __restrict__ out)
{
    __shared__ __align__(16) char smem[61952];
    __bf16* As = (__bf16*)smem;                     // [128][64] chunk-swizzled
    __bf16* Bs = (__bf16*)(smem + 16384);           // [256][64] chunk-swizzled
    int*    sS = (int*)(smem + 49152);              // [5*128] spatial bases
    float4* sW = (float4*)(smem + 51712);           // [5*128] corner weights

    const int tid  = threadIdx.x;
    const int lane = tid & 63, wv = tid >> 6;       // 8 waves
    const int wm = wv & 1, wn = wv >> 1;            // m-half 64 px, n-quarter 64
    const int l15 = lane & 15, q = lane >> 4;

    // bijective chunked XCD swizzle: 196 = 8*24 + 4
    const int xcd = blockIdx.x & 7, ib = blockIdx.x >> 3;
    const int wg  = (xcd < 4) ? xcd * 25 + ib : 100 + (xcd - 4) * 24 + ib;
    const int m0  = wg * MT;

    compute_params(offs, msk, m0, 0, 5, sS, sW, tid);

    v4f acc[4][4];
#pragma unroll
    for (int i = 0; i < 4; ++i)
#pragma unroll
        for (int j = 0; j < 4; ++j) acc[i][j] = (v4f)0.f;

    __syncthreads();                                // params ready

    const int pxl = tid >> 2, c2 = tid & 3;         // pixel row, chunk pair
    v8bf ga0, ga1, ga2, ga3, gb0, gb1, gb2, gb3;
    float4 cw;

#define GATHER(E, KQ)                                                   \
    { const int b_ = sS[E] + ((KQ) << 6) + c2 * 8;                      \
      cw  = sW[E];                                                      \
      ga0 = *(const v8bf*)(xb + b_);                                    \
      ga1 = *(const v8bf*)(xb + b_ + 256);                              \
      ga2 = *(const v8bf*)(xb + b_ + 14336);                            \
      ga3 = *(const v8bf*)(xb + b_ + 14592);                            \
      gb0 = *(const v8bf*)(xb + b_ + 32);                               \
      gb1 = *(const v8bf*)(xb + b_ + 288);                              \
      gb2 = *(const v8bf*)(xb + b_ + 14368);                            \
      gb3 = *(const v8bf*)(xb + b_ + 14624); }

    GATHER(pxl, 0)                                  // prefetch ks=0 (tap 0)

#pragma unroll 1
    for (int ks = 0; ks < 36; ++ks) {
        // combine in-flight gathers (VALU)
        v8bf r0, r1;
#pragma unroll
        for (int j = 0; j < 8; ++j) {
            r0[j] = (__bf16)(cw.x * (float)ga0[j] + cw.y * (float)ga1[j]
                           + cw.z * (float)ga2[j] + cw.w * (float)ga3[j]);
            r1[j] = (__bf16)(cw.x * (float)gb0[j] + cw.y * (float)gb1[j]
                           + cw.z * (float)gb2[j] + cw.w * (float)gb3[j]);
        }

        __syncthreads();                            // #1: prev MFMA reads done

        *(v8bf*)(As + pxl * 64 + (((c2)     ^ (pxl & 7)) << 3)) = r0;
        *(v8bf*)(As + pxl * 64 + (((c2 + 4) ^ (pxl & 7)) << 3)) = r1;

        const int k0 = ks << 6;
#pragma unroll
        for (int t = 0; t < 4; ++t) {               // stage B 32KB (verified)
            const int brow = t * 64 + (wv << 3) + (lane >> 3);
            const int blc  = (lane & 7) ^ (brow & 7);
            async_copy16(bp + (size_t)brow * KG + k0 + blc * 8,
                         smem + 16384 + ((t * 8 + wv) << 10));
        }

        if (ks == 19) {                             // roll params to taps 5..8
            compute_params(offs, msk, m0, 5, 4, sS, sW, tid);
            __syncthreads();
        }

        if (ks < 35) {                              // prefetch next k-step
            const int ks1 = ks + 1;
            const int tap = ks1 >> 2;
            const int e = (tap >= 5 ? tap - 5 : tap) * MT + pxl;
            GATHER(e, ks1 & 3)
        }

        __syncthreads();                            // #2: As/Bs ready

#pragma unroll
        for (int kf = 0; kf < 2; ++kf) {
            v8bf afr[4], bfr[4];
#pragma unroll
            for (int mt = 0; mt < 4; ++mt) {
                const int row = wm * 64 + mt * 16 + l15;
                const int pch = (kf * 4 + q) ^ (row & 7);
                afr[mt] = *(const v8bf*)(As + row * 64 + pch * 8);
            }
#pragma unroll
            for (int nt = 0; nt < 4; ++nt) {
                const int row = wn * 64 + nt * 16 + l15;
                const int pch = (kf * 4 + q) ^ (row & 7);
                bfr[nt] = *(const v8bf*)(Bs + row * 64 + pch * 8);
            }
#pragma unroll
            for (int mt = 0; mt < 4; ++mt)
#pragma unroll
                for (int nt = 0; nt < 4; ++nt)
                    acc[mt][nt] = __builtin_amdgcn_mfma_f32_16x16x32_bf16(
                        afr[mt], bfr[nt], acc[mt][nt], 0, 0, 0);
        }
    }
#undef GATHER

    // ---- epilogue: per-wave LDS transpose (no cross-wave sharing)
    __syncthreads();
    float* epi = (float*)smem + wv * 1104;          // 64 x 17 floats per wave
    const int pg_l = m0 + wm * 64 + lane;
    const int n_l  = pg_l / SPIX;
    float* outp = out + (size_t)n_l * (COUT * SPIX) + (pg_l - n_l * SPIX);

#pragma unroll
    for (int nt = 0; nt < 4; ++nt) {
        const float bv = bias[wn * 64 + nt * 16 + l15];
#pragma unroll
        for (int mt = 0; mt < 4; ++mt)
#pragma unroll
            for (int r = 0; r < 4; ++r)
                epi[(mt * 16 + q * 4 + r) * 17 + l15] = acc[mt][nt][r] + bv;
        // wave-local region: lgkmcnt ordering suffices, no barrier
#pragma unroll
        for (int oc = 0; oc < 16; ++oc)
            outp[(size_t)(wn * 64 + nt * 16 + oc) * SPIX] = epi[lane * 17 + oc];
    }
}

// ---------- fp32 fallback (round-1 verified, no workspace)
#define BM 64
#define BN 64
#define BKF 32
#define AST 68
#define BST 68
#define CST 65
__global__ __launch_bounds__(256) void mdcn_fallback(
    const float* __restrict__ xs, const float* __restrict__ offs,
    const float* __restrict__ msk, const float* __restrict__ wraw,
    const float* __restrict__ bias, float* __restrict__ out)
{
    __shared__ float smem[BKF * AST + BKF * BST];
    __shared__ int   sBase[4][BM];
    __shared__ float sWgt[4][BM];
    float (*At)[AST] = (float (*)[AST])smem;
    float (*Bt)[BST] = (float (*)[BST])(smem + BKF * AST);
    float (*Cs)[CST] = (float (*)[CST])smem;
    const int tid = threadIdx.x;
    const int m0 = blockIdx.x * BM;
    const int o0 = blockIdx.y * BN;
    const int n  = m0 / SPIX;
    const int s0 = m0 - n * SPIX;
    const int tx = tid & 15, ty = tid >> 4;
    float acc[4][4] = {};
    for (int k = 0; k < 9; ++k) {
        if (tid < BM) {
            const int s = s0 + tid;
            const int h = s / W_;
            const int w = s - h * W_;
            const int kY = k / 3, kX = k - kY * 3;
            const float dy = offs[(size_t)n * (18 * SPIX) + (size_t)(2 * k) * SPIX + s];
            const float dx = offs[(size_t)n * (18 * SPIX) + (size_t)(2 * k + 1) * SPIX + s];
            const float mk = msk[(size_t)n * (9 * SPIX) + (size_t)k * SPIX + s];
            const float py = dy + (float)(kY + h - 1);
            const float px = dx + (float)(kX + w - 1);
            const float fy0 = floorf(py), fx0 = floorf(px);
            const int y0 = (int)fy0, x0 = (int)fx0;
            const float wy1 = py - fy0, wx1 = px - fx0;
            const float wy0 = 1.0f - wy1, wx0 = 1.0f - wx1;
#pragma unroll
            for (int t = 0; t < 4; ++t) {
                const int yi = y0 + (t >> 1), xi = x0 + (t & 1);
                const bool valid = (yi >= 0) & (yi < H_) & (xi >= 0) & (xi < W_);
                const int yc = min(max(yi, 0), H_ - 1);
                const int xc = min(max(xi, 0), W_ - 1);
                float wt = ((t >> 1) ? wy1 : wy0) * ((t & 1) ? wx1 : wx0) * mk;
                sBase[t][tid] = n * (CIN * SPIX) + yc * W_ + xc;
                sWgt[t][tid] = valid ? wt : 0.0f;
            }
        }
        __syncthreads();
        for (int c0 = 0; c0 < CIN; c0 += BKF) {
#pragma unroll
            for (int i = 0; i < 8; ++i) {
                int idx = tid + i * 256;
                int row = idx >> 5, cc = idx & 31;
                int ce = (c0 + cc) * SPIX;
                At[cc][row] = sWgt[0][row] * xs[sBase[0][row] + ce]
                            + sWgt[1][row] * xs[sBase[1][row] + ce]
                            + sWgt[2][row] * xs[sBase[2][row] + ce]
                            + sWgt[3][row] * xs[sBase[3][row] + ce];
            }
#pragma unroll
            for (int i = 0; i < 8; ++i) {
                int idx = tid + i * 256;
                int kf = idx >> 6, o = idx & 63;
                Bt[kf][o] = wraw[(size_t)(o0 + o) * KG + (c0 + kf) * 9 + k];
            }
            __syncthreads();
#pragma unroll
            for (int kf = 0; kf < BKF; ++kf) {
                const float4 a = *(const float4*)&At[kf][ty * 4];
                const float4 b = *(const float4*)&Bt[kf][tx * 4];
                acc[0][0] = fmaf(a.x, b.x, acc[0][0]); acc[0][1] = fmaf(a.x, b.y, acc[0][1]);
                acc[0][2] = fmaf(a.x, b.z, acc[0][2]); acc[0][3] = fmaf(a.x, b.w, acc[0][3]);
                acc[1][0] = fmaf(a.y, b.x, acc[1][0]); acc[1][1] = fmaf(a.y, b.y, acc[1][1]);
                acc[1][2] = fmaf(a.y, b.z, acc[1][2]); acc[1][3] = fmaf(a.y, b.w, acc[1][3]);
                acc[2][0] = fmaf(a.z, b.x, acc[2][0]); acc[2][1] = fmaf(a.z, b.y, acc[2][1]);
                acc[2][2] = fmaf(a.z, b.z, acc[2][2]); acc[2][3] = fmaf(a.z, b.w, acc[2][3]);
                acc[3][0] = fmaf(a.w, b.x, acc[3][0]); acc[3][1] = fmaf(a.w, b.y, acc[3][1]);
                acc[3][2] = fmaf(a.w, b.z, acc[3][2]); acc[3][3] = fmaf(a.w, b.w, acc[3][3]);
            }
            __syncthreads();
        }
    }
#pragma unroll
    for (int i = 0; i < 4; ++i)
#pragma unroll
        for (int j = 0; j < 4; ++j)
            Cs[ty * 4 + i][tx * 4 + j] = acc[i][j] + bias[o0 + tx * 4 + j];
    __syncthreads();
    const int pix = tid & 63, ob = tid >> 6;
    float* outp = out + (size_t)n * COUT * SPIX + s0 + pix;
#pragma unroll
    for (int r = 0; r < 16; ++r) {
        int o = r * 4 + ob;
        outp[(size_t)(o0 + o) * SPIX] = Cs[pix][o];
    }
}

extern "C" void kernel_launch(void* const* d_in, const int* in_sizes, int n_in,
                              void* d_out, int out_size, void* d_ws, size_t ws_size,
                              hipStream_t stream) {
    const float* x    = (const float*)d_in[0];
    const float* offs = (const float*)d_in[1];
    const float* msk  = (const float*)d_in[2];
    const float* w    = (const float*)d_in[3];
    const float* bias = (const float*)d_in[4];
    float* out = (float*)d_out;

    const size_t GUARD    = (size_t)4 << 20;                         // 4 MB
    const size_t xb_bytes = (size_t)NB * SPIX * CIN * sizeof(__bf16);
    const size_t bp_bytes = (size_t)KG * COUT * sizeof(__bf16);
    const size_t need     = GUARD + xb_bytes + GUARD + bp_bytes;

    if (ws_size >= need) {
        __bf16* xb = (__bf16*)((char*)d_ws + GUARD);
        __bf16* bp = (__bf16*)((char*)d_ws + GUARD + xb_bytes + GUARD);
        prep_x<<<dim3(49, 4, 8), 256, 0, stream>>>(x, xb);
        prep_w<<<dim3((COUT * KG + 255) / 256), 256, 0, stream>>>(w, bp);
        mdcn_fused3<<<dim3(NBLK), 512, 0, stream>>>(xb, offs, msk, bp, bias, out);
    } else {
        mdcn_fallback<<<dim3(MTOT / BM, COUT / BN), 256, 0, stream>>>(
            x, offs, msk, w, bias, out);
    }
}

// Round 4
// 155.975 us; speedup vs baseline: 1.5527x; 1.0439x over previous
//
#include <hip/hip_runtime.h>
#include <math.h>

#define H_ 56
#define W_ 56
#define CIN 256
#define COUT 256
#define NB 8
#define SPIX 3136
#define KG 2304
#define MTOT 25088
#define MT 128
#define NBLK 196   // MTOT / MT
#define GUARD_PX 2048                 // 1 MB guard each side of xb (512 B/px)

typedef __bf16 v8bf __attribute__((ext_vector_type(8)));
typedef float  v4f  __attribute__((ext_vector_type(4)));

#define WAIT_VM(N)  do { asm volatile("s_waitcnt vmcnt(" #N ")" ::: "memory"); \
                         __builtin_amdgcn_sched_barrier(0); } while (0)
#define WAIT_LGKM0  do { asm volatile("s_waitcnt lgkmcnt(0)" ::: "memory"); \
                         __builtin_amdgcn_sched_barrier(0); } while (0)
#define BARR        do { asm volatile("s_barrier" ::: "memory"); } while (0)

__device__ __forceinline__ void async_copy16(const void* g, void* l) {
    __builtin_amdgcn_global_load_lds(
        (const __attribute__((address_space(1))) void*)g,
        (__attribute__((address_space(3))) void*)l, 16, 0, 0);
}

// ---------- merged pre-kernel: z<8 -> NCHW fp32 to NHWC bf16 (image z);
//                               z==8 -> weight (Cout,Cin,3,3) -> Bp[o][tap*256+c]
__global__ __launch_bounds__(256) void prep_xw(const float* __restrict__ x,
                                               const float* __restrict__ w,
                                               __bf16* __restrict__ xb,
                                               __bf16* __restrict__ bp) {
    __shared__ float tile[64][65];
    const int tid = threadIdx.x;
    if (blockIdx.z < 8) {
        const int n = blockIdx.z, c0 = blockIdx.y * 64, s0 = blockIdx.x * 64;
        const float* xp = x + (size_t)n * CIN * SPIX;
        __bf16* xo = xb + (size_t)n * SPIX * CIN;
#pragma unroll
        for (int i = 0; i < 16; ++i) {
            int idx = tid + i * 256;
            int cr = idx >> 6, sc = idx & 63;
            tile[cr][sc] = xp[(c0 + cr) * SPIX + s0 + sc];
        }
        __syncthreads();
#pragma unroll
        for (int i = 0; i < 16; ++i) {
            int idx = tid + i * 256;
            int sr = idx >> 6, cc = idx & 63;
            xo[(s0 + sr) * CIN + c0 + cc] = (__bf16)tile[cc][sr];
        }
    } else {
        const int base = (blockIdx.y * 49 + blockIdx.x) * 256 + tid;
        for (int i = base; i < COUT * KG; i += 196 * 256) {
            const int o = i / KG;
            const int rem = i - o * KG;
            const int c = rem / 9;
            const int tap = rem - c * 9;
            bp[(size_t)o * KG + tap * 256 + c] = (__bf16)w[i];
        }
    }
}

// ---------- bilinear params for ALL 9 taps of this block's 128 px.
// Base is UNCLAMPED (round-2 semantics): the y0+1/x0+1 corner reads are
// base-relative, so base must not be moved while any corner is valid.
// Weight-0 corners read into the zeroed 1MB guard bands around xb.
// The +/-GUARD_PX safety clamp only fires when ALL weights are provably 0.
__device__ __forceinline__ void compute_params(
    const float* __restrict__ offs, const float* __restrict__ msk,
    int m0, int* sS, float4* sW, int tid)
{
    for (int idx = tid; idx < 9 * MT; idx += 512) {
        const int tl = idx >> 7, pl = idx & 127;
        const int pg = m0 + pl;
        const int n  = pg / SPIX;
        const int s  = pg - n * SPIX;
        const int h  = s / W_, w = s - h * W_;
        const int kY = tl / 3, kX = tl - kY * 3;
        const float dy = offs[n * (18 * SPIX) + (2 * tl) * SPIX + s];
        const float dx = offs[n * (18 * SPIX) + (2 * tl + 1) * SPIX + s];
        const float mk = msk[n * (9 * SPIX) + tl * SPIX + s];
        const float py = dy + (float)(kY + h - 1);   // PAD=1,STRIDE=1,DIL=1
        const float px = dx + (float)(kX + w - 1);
        const float fy0 = floorf(py), fx0 = floorf(px);
        const int y0 = (int)fy0, x0 = (int)fx0;
        const float wy1 = py - fy0, wx1 = px - fx0;
        const float wy0 = 1.f - wy1, wx0 = 1.f - wx1;
        const bool yv0 = (y0 >= 0) & (y0 < H_);
        const bool yv1 = (y0 + 1 >= 0) & (y0 + 1 < H_);
        const bool xv0 = (x0 >= 0) & (x0 < W_);
        const bool xv1 = (x0 + 1 >= 0) & (x0 + 1 < W_);
        float4 wt;
        wt.x = (yv0 & xv0) ? wy0 * wx0 * mk : 0.f;
        wt.y = (yv0 & xv1) ? wy0 * wx1 * mk : 0.f;
        wt.z = (yv1 & xv0) ? wy1 * wx0 * mk : 0.f;
        wt.w = (yv1 & xv1) ? wy1 * wx1 * mk : 0.f;
        int base = n * SPIX + y0 * W_ + x0;
        base = min(max(base, -GUARD_PX), NB * SPIX - 58 + GUARD_PX);
        sS[idx] = base * CIN;
        sW[idx] = wt;
    }
}

// ---------- fused deformable-gather + bf16 MFMA GEMM.
// 128 px x 256 out per block, full K, grid 196. Double-buffered A/B in LDS,
// ONE raw s_barrier per K-step, counted vmcnt (T3/T4): B staging asyncs and
// next-step gathers stay in flight across the barrier; no vmcnt(0) drain in
// the main loop. setprio(1) around the MFMA cluster (T5).
// vmcnt ledger (in-order retirement): entry of iter ks -> 8 gathers(ks+1)
// outstanding; +4 asyncs; vmcnt(4) retires the 8 gathers; +8 gathers(ks+2);
// vmcnt(8) retires the 4 asyncs; s_barrier.
__global__ __launch_bounds__(512, 2) void mdcn_fused4(
    const __bf16* __restrict__ xb,     // NHWC bf16 (1MB zeroed guard both sides)
    const float*  __restrict__ offs,
    const float*  __restrict__ msk,
    const __bf16* __restrict__ bp,     // [COUT][KG] tap-major K
    const float*  __restrict__ bias,
    float*        __restrict__ out)
{
    __shared__ __align__(16) char smem[121344];
    // As0 @0 (16K) | As1 @16384 | Bs0 @32768 (32K) | Bs1 @65536
    int*    sS = (int*)(smem + 98304);              // [9*128]
    float4* sW = (float4*)(smem + 102912);          // [9*128]

    const int tid  = threadIdx.x;
    const int lane = tid & 63, wv = tid >> 6;       // 8 waves
    const int wm = wv & 1, wn = wv >> 1;            // m-half 64 px, n-quarter 64
    const int l15 = lane & 15, q = lane >> 4;

    // bijective chunked XCD swizzle: 196 = 8*24 + 4
    const int xcd = blockIdx.x & 7, ib = blockIdx.x >> 3;
    const int wg  = (xcd < 4) ? xcd * 25 + ib : 100 + (xcd - 4) * 24 + ib;
    const int m0  = wg * MT;

    compute_params(offs, msk, m0, sS, sW, tid);

    v4f acc[4][4];
#pragma unroll
    for (int i = 0; i < 4; ++i)
#pragma unroll
        for (int j = 0; j < 4; ++j) acc[i][j] = (v4f)0.f;

    __syncthreads();                                // params visible (full drain, once)

    const int pxl = tid >> 2, c2 = tid & 3;         // pixel row, chunk pair
    v8bf ga0, ga1, ga2, ga3, gb0, gb1, gb2, gb3;
    float4 cw;

#define GATHER(E, KQ)                                                   \
    { const int b_ = sS[E] + ((KQ) << 6) + c2 * 8;                      \
      cw  = sW[E];                                                      \
      ga0 = *(const v8bf*)(xb + b_);                                    \
      ga1 = *(const v8bf*)(xb + b_ + 256);                              \
      ga2 = *(const v8bf*)(xb + b_ + 14336);                            \
      ga3 = *(const v8bf*)(xb + b_ + 14592);                            \
      gb0 = *(const v8bf*)(xb + b_ + 32);                               \
      gb1 = *(const v8bf*)(xb + b_ + 288);                              \
      gb2 = *(const v8bf*)(xb + b_ + 14368);                            \
      gb3 = *(const v8bf*)(xb + b_ + 14624); }

#define COMBINE_STORE(AP)                                               \
    { v8bf r0, r1;                                                      \
      _Pragma("unroll")                                                 \
      for (int j = 0; j < 8; ++j) {                                     \
        r0[j] = (__bf16)(cw.x * (float)ga0[j] + cw.y * (float)ga1[j]    \
                       + cw.z * (float)ga2[j] + cw.w * (float)ga3[j]);  \
        r1[j] = (__bf16)(cw.x * (float)gb0[j] + cw.y * (float)gb1[j]    \
                       + cw.z * (float)gb2[j] + cw.w * (float)gb3[j]);  \
      }                                                                 \
      *(v8bf*)((AP) + pxl * 64 + (((c2)     ^ (pxl & 7)) << 3)) = r0;   \
      *(v8bf*)((AP) + pxl * 64 + (((c2 + 4) ^ (pxl & 7)) << 3)) = r1; }

#define STAGE_B(K0, LB)                                                 \
    { _Pragma("unroll")                                                 \
      for (int t = 0; t < 4; ++t) {                                     \
        const int brow = t * 64 + (wv << 3) + (lane >> 3);              \
        const int blc  = (lane & 7) ^ (brow & 7);                       \
        async_copy16(bp + (size_t)brow * KG + (K0) + blc * 8,           \
                     (LB) + ((t * 8 + wv) << 10)); }

    // ---------- prologue: fill A0/B0 for step 0, gathers for step 1 in flight
    GATHER(pxl, 0)                                  // step 0 (tap 0, kq 0)
    COMBINE_STORE((__bf16*)smem)                    // -> As0 (drains gathers)
    STAGE_B(0, smem + 32768) }                      // -> Bs0 (4 asyncs)
    GATHER(pxl, 1)                                  // step 1 (tap 0, kq 1)
    WAIT_LGKM0;                                     // A0 write drained
    WAIT_VM(8);                                     // B0 asyncs drained; 8 gathers fly
    BARR;

    char* ac = smem;          char* an = smem + 16384;
    char* bc = smem + 32768;  char* bn = smem + 65536;

#pragma unroll 1
    for (int ks = 0; ks < 36; ++ks) {
        if (ks < 35) {
            STAGE_B((ks + 1) << 6, bn) }            // 4 asyncs -> B[nxt]
            WAIT_VM(4);                             // gathers(ks+1) arrived; asyncs fly
            COMBINE_STORE((__bf16*)an)              // A(ks+1) -> A[nxt]
            if (ks < 34) {
                const int st = ks + 2;
                GATHER((st >> 2) * MT + pxl, st & 3)  // 8 loads stay in flight
            }
        }

        // ---- MFMA on A[cur]/B[cur]
        __builtin_amdgcn_s_setprio(1);
#pragma unroll
        for (int kf = 0; kf < 2; ++kf) {
            v8bf afr[4], bfr[4];
#pragma unroll
            for (int mt = 0; mt < 4; ++mt) {
                const int row = wm * 64 + mt * 16 + l15;
                const int pch = (kf * 4 + q) ^ (row & 7);
                afr[mt] = *(const v8bf*)((__bf16*)ac + row * 64 + pch * 8);
            }
#pragma unroll
            for (int nt = 0; nt < 4; ++nt) {
                const int row = wn * 64 + nt * 16 + l15;
                const int pch = (kf * 4 + q) ^ (row & 7);
                bfr[nt] = *(const v8bf*)((__bf16*)bc + row * 64 + pch * 8);
            }
#pragma unroll
            for (int mt = 0; mt < 4; ++mt)
#pragma unroll
                for (int nt = 0; nt < 4; ++nt)
                    acc[mt][nt] = __builtin_amdgcn_mfma_f32_16x16x32_bf16(
                        afr[mt], bfr[nt], acc[mt][nt], 0, 0, 0);
        }
        __builtin_amdgcn_s_setprio(0);

        if (ks < 34) {
            WAIT_LGKM0;                             // A[nxt] writes drained
            WAIT_VM(8);                             // B[nxt] asyncs done; gathers fly
            BARR;
        } else if (ks == 34) {
            WAIT_LGKM0;
            WAIT_VM(0);                             // nothing else in flight
            BARR;
        }
        char* t;
        t = ac; ac = an; an = t;
        t = bc; bc = bn; bn = t;
    }
#undef GATHER
#undef COMBINE_STORE
#undef STAGE_B

    // ---- epilogue: per-wave LDS transpose (wave-local region)
    WAIT_LGKM0;
    BARR;                                           // all MFMA reads of smem done
    float* epi = (float*)smem + wv * 1104;          // 64 x 17 floats per wave
    const int pg_l = m0 + wm * 64 + lane;
    const int n_l  = pg_l / SPIX;
    float* outp = out + (size_t)n_l * (COUT * SPIX) + (pg_l - n_l * SPIX);

#pragma unroll
    for (int nt = 0; nt < 4; ++nt) {
        const float bv = bias[wn * 64 + nt * 16 + l15];
#pragma unroll
        for (int mt = 0; mt < 4; ++mt)
#pragma unroll
            for (int r = 0; r < 4; ++r)
                epi[(mt * 16 + q * 4 + r) * 17 + l15] = acc[mt][nt][r] + bv;
#pragma unroll
        for (int oc = 0; oc < 16; ++oc)
            outp[(size_t)(wn * 64 + nt * 16 + oc) * SPIX] = epi[lane * 17 + oc];
    }
}

// ---------- fp32 fallback (round-1 verified, no workspace)
#define BM 64
#define BN 64
#define BKF 32
#define AST 68
#define BST 68
#define CST 65
__global__ __launch_bounds__(256) void mdcn_fallback(
    const float* __restrict__ xs, const float* __restrict__ offs,
    const float* __restrict__ msk, const float* __restrict__ wraw,
    const float* __restrict__ bias, float* __restrict__ out)
{
    __shared__ float smem[BKF * AST + BKF * BST];
    __shared__ int   sBase[4][BM];
    __shared__ float sWgt[4][BM];
    float (*At)[AST] = (float (*)[AST])smem;
    float (*Bt)[BST] = (float (*)[BST])(smem + BKF * AST);
    float (*Cs)[CST] = (float (*)[CST])smem;
    const int tid = threadIdx.x;
    const int m0 = blockIdx.x * BM;
    const int o0 = blockIdx.y * BN;
    const int n  = m0 / SPIX;
    const int s0 = m0 - n * SPIX;
    const int tx = tid & 15, ty = tid >> 4;
    float acc[4][4] = {};
    for (int k = 0; k < 9; ++k) {
        if (tid < BM) {
            const int s = s0 + tid;
            const int h = s / W_;
            const int w = s - h * W_;
            const int kY = k / 3, kX = k - kY * 3;
            const float dy = offs[(size_t)n * (18 * SPIX) + (size_t)(2 * k) * SPIX + s];
            const float dx = offs[(size_t)n * (18 * SPIX) + (size_t)(2 * k + 1) * SPIX + s];
            const float mk = msk[(size_t)n * (9 * SPIX) + (size_t)k * SPIX + s];
            const float py = dy + (float)(kY + h - 1);
            const float px = dx + (float)(kX + w - 1);
            const float fy0 = floorf(py), fx0 = floorf(px);
            const int y0 = (int)fy0, x0 = (int)fx0;
            const float wy1 = py - fy0, wx1 = px - fx0;
            const float wy0 = 1.0f - wy1, wx0 = 1.0f - wx1;
#pragma unroll
            for (int t = 0; t < 4; ++t) {
                const int yi = y0 + (t >> 1), xi = x0 + (t & 1);
                const bool valid = (yi >= 0) & (yi < H_) & (xi >= 0) & (xi < W_);
                const int yc = min(max(yi, 0), H_ - 1);
                const int xc = min(max(xi, 0), W_ - 1);
                float wt = ((t >> 1) ? wy1 : wy0) * ((t & 1) ? wx1 : wx0) * mk;
                sBase[t][tid] = n * (CIN * SPIX) + yc * W_ + xc;
                sWgt[t][tid] = valid ? wt : 0.0f;
            }
        }
        __syncthreads();
        for (int c0 = 0; c0 < CIN; c0 += BKF) {
#pragma unroll
            for (int i = 0; i < 8; ++i) {
                int idx = tid + i * 256;
                int row = idx >> 5, cc = idx & 31;
                int ce = (c0 + cc) * SPIX;
                At[cc][row] = sWgt[0][row] * xs[sBase[0][row] + ce]
                            + sWgt[1][row] * xs[sBase[1][row] + ce]
                            + sWgt[2][row] * xs[sBase[2][row] + ce]
                            + sWgt[3][row] * xs[sBase[3][row] + ce];
            }
#pragma unroll
            for (int i = 0; i < 8; ++i) {
                int idx = tid + i * 256;
                int kf = idx >> 6, o = idx & 63;
                Bt[kf][o] = wraw[(size_t)(o0 + o) * KG + (c0 + kf) * 9 + k];
            }
            __syncthreads();
#pragma unroll
            for (int kf = 0; kf < BKF; ++kf) {
                const float4 a = *(const float4*)&At[kf][ty * 4];
                const float4 b = *(const float4*)&Bt[kf][tx * 4];
                acc[0][0] = fmaf(a.x, b.x, acc[0][0]); acc[0][1] = fmaf(a.x, b.y, acc[0][1]);
                acc[0][2] = fmaf(a.x, b.z, acc[0][2]); acc[0][3] = fmaf(a.x, b.w, acc[0][3]);
                acc[1][0] = fmaf(a.y, b.x, acc[1][0]); acc[1][1] = fmaf(a.y, b.y, acc[1][1]);
                acc[1][2] = fmaf(a.y, b.z, acc[1][2]); acc[1][3] = fmaf(a.y, b.w, acc[1][3]);
                acc[2][0] = fmaf(a.z, b.x, acc[2][0]); acc[2][1] = fmaf(a.z, b.y, acc[2][1]);
                acc[2][2] = fmaf(a.z, b.z, acc[2][2]); acc[2][3] = fmaf(a.z, b.w, acc[2][3]);
                acc[3][0] = fmaf(a.w, b.x, acc[3][0]); acc[3][1] = fmaf(a.w, b.y, acc[3][1]);
                acc[3][2] = fmaf(a.w, b.z, acc[3][2]); acc[3][3] = fmaf(a.w, b.w, acc[3][3]);
            }
            __syncthreads();
        }
    }
#pragma unroll
    for (int i = 0; i < 4; ++i)
#pragma unroll
        for (int j = 0; j < 4; ++j)
            Cs[ty * 4 + i][tx * 4 + j] = acc[i][j] + bias[o0 + tx * 4 + j];
    __syncthreads();
    const int pix = tid & 63, ob = tid >> 6;
    float* outp = out + (size_t)n * COUT * SPIX + s0 + pix;
#pragma unroll
    for (int r = 0; r < 16; ++r) {
        int o = r * 4 + ob;
        outp[(size_t)(o0 + o) * SPIX] = Cs[pix][o];
    }
}

extern "C" void kernel_launch(void* const* d_in, const int* in_sizes, int n_in,
                              void* d_out, int out_size, void* d_ws, size_t ws_size,
                              hipStream_t stream) {
    const float* x    = (const float*)d_in[0];
    const float* offs = (const float*)d_in[1];
    const float* msk  = (const float*)d_in[2];
    const float* w    = (const float*)d_in[3];
    const float* bias = (const float*)d_in[4];
    float* out = (float*)d_out;

    const size_t GUARD_B  = (size_t)GUARD_PX * CIN * sizeof(__bf16);   // 1 MB
    const size_t xb_bytes = (size_t)NB * SPIX * CIN * sizeof(__bf16);
    const size_t bp_bytes = (size_t)KG * COUT * sizeof(__bf16);
    const size_t need     = GUARD_B + xb_bytes + GUARD_B + bp_bytes;

    if (ws_size >= need) {
        __bf16* xb = (__bf16*)((char*)d_ws + GUARD_B);
        __bf16* bp = (__bf16*)((char*)d_ws + GUARD_B + xb_bytes + GUARD_B);
        // zero the guards so weight-0 corner reads are 0, never NaN-garbage
        hipMemsetAsync(d_ws, 0, GUARD_B, stream);
        hipMemsetAsync((char*)d_ws + GUARD_B + xb_bytes, 0, GUARD_B, stream);
        prep_xw<<<dim3(49, 4, 9), 256, 0, stream>>>(x, w, xb, bp);
        mdcn_fused4<<<dim3(NBLK), 512, 0, stream>>>(xb, offs, msk, bp, bias, out);
    } else {
        mdcn_fallback<<<dim3(MTOT / BM, COUT / BN), 256, 0, stream>>>(
            x, offs, msk, w, bias, out);
    }
}